// Round 1
// baseline (277.825 us; speedup 1.0000x reference)
//
#include <hip/hip_runtime.h>
#include <hip/hip_bf16.h>
#include <cstdint>

#define D_MODEL 2048
#define N_BATCH 16384

typedef __attribute__((ext_vector_type(8))) __bf16 bf16x8;
typedef __attribute__((ext_vector_type(4))) float f32x4;

__device__ __forceinline__ unsigned short f2bf(float f) {
    unsigned int u = __builtin_bit_cast(unsigned int, f);
    u += 0x7fffu + ((u >> 16) & 1u);
    return (unsigned short)(u >> 16);
}

// ---------------- LayerNorm: x fp32 [B][D] -> h bf16 [B][D] ----------------
__global__ __launch_bounds__(256) void ln_kernel(
    const float* __restrict__ x, const float* __restrict__ gamma,
    const float* __restrict__ beta, unsigned short* __restrict__ h)
{
    const int row = blockIdx.x;
    const int t = threadIdx.x;
    const float4* x4 = reinterpret_cast<const float4*>(x + (long)row * D_MODEL);
    float4 a = x4[t];
    float4 b = x4[256 + t];
    float s  = a.x + a.y + a.z + a.w + b.x + b.y + b.z + b.w;
    float ss = a.x*a.x + a.y*a.y + a.z*a.z + a.w*a.w
             + b.x*b.x + b.y*b.y + b.z*b.z + b.w*b.w;
    #pragma unroll
    for (int off = 32; off; off >>= 1) {
        s  += __shfl_xor(s, off);
        ss += __shfl_xor(ss, off);
    }
    __shared__ float red[8];
    const int lane = t & 63, wid = t >> 6;
    if (lane == 0) { red[wid*2] = s; red[wid*2+1] = ss; }
    __syncthreads();
    s  = red[0] + red[2] + red[4] + red[6];
    ss = red[1] + red[3] + red[5] + red[7];
    const float mean = s * (1.0f / D_MODEL);
    const float var  = ss * (1.0f / D_MODEL) - mean * mean;
    const float inv  = rsqrtf(var + 1e-5f);

    const float4* g4  = reinterpret_cast<const float4*>(gamma);
    const float4* be4 = reinterpret_cast<const float4*>(beta);
    ushort4* h4 = reinterpret_cast<ushort4*>(h + (long)row * D_MODEL);
    {
        float4 g = g4[t], be = be4[t];
        ushort4 o;
        o.x = f2bf((a.x - mean) * inv * g.x + be.x);
        o.y = f2bf((a.y - mean) * inv * g.y + be.y);
        o.z = f2bf((a.z - mean) * inv * g.z + be.z);
        o.w = f2bf((a.w - mean) * inv * g.w + be.w);
        h4[t] = o;
    }
    {
        float4 g = g4[256 + t], be = be4[256 + t];
        ushort4 o;
        o.x = f2bf((b.x - mean) * inv * g.x + be.x);
        o.y = f2bf((b.y - mean) * inv * g.y + be.y);
        o.z = f2bf((b.z - mean) * inv * g.z + be.z);
        o.w = f2bf((b.w - mean) * inv * g.w + be.w);
        h4[256 + t] = o;
    }
}

// ------------- transpose + convert: out[k][j] = bf16(in[j][k]) -------------
__global__ __launch_bounds__(256) void transpose_f32_to_bf16(
    const float* __restrict__ in, unsigned short* __restrict__ out, int Dm)
{
    __shared__ float tile[32][33];
    const int nb = Dm >> 5;
    const int k0 = (blockIdx.x % nb) * 32;
    const int j0 = (blockIdx.x / nb) * 32;
    const int tx = threadIdx.x & 31, ty0 = threadIdx.x >> 5;
    #pragma unroll
    for (int i = 0; i < 32; i += 8) {
        int j = ty0 + i;
        tile[j][tx] = in[(long)(j0 + j) * Dm + k0 + tx];
    }
    __syncthreads();
    #pragma unroll
    for (int i = 0; i < 32; i += 8) {
        int kk = ty0 + i;
        out[(long)(k0 + kk) * Dm + j0 + tx] = f2bf(tile[tx][kk]);
    }
}

// ---------------- elementwise convert fp32 -> bf16 ----------------
__global__ __launch_bounds__(256) void convert_bf16(
    const float* __restrict__ in, unsigned short* __restrict__ out, long n)
{
    long i = ((long)blockIdx.x * 256 + threadIdx.x) * 8;
    if (i >= n) return;
    const float4* in4 = reinterpret_cast<const float4*>(in + i);
    float4 a = in4[0], b = in4[1];
    union { unsigned short u[8]; uint4 v; } o;
    o.u[0] = f2bf(a.x); o.u[1] = f2bf(a.y); o.u[2] = f2bf(a.z); o.u[3] = f2bf(a.w);
    o.u[4] = f2bf(b.x); o.u[5] = f2bf(b.y); o.u[6] = f2bf(b.z); o.u[7] = f2bf(b.w);
    *reinterpret_cast<uint4*>(out + i) = o.v;
}

// ---------------- b_c[n] = b_o[n] + sum_j w_o[n][j]*b_v[j] (fp32) ----------------
__global__ __launch_bounds__(256) void bias_combine(
    const float* __restrict__ w_o, const float* __restrict__ b_v,
    const float* __restrict__ b_o, float* __restrict__ b_c)
{
    const int n = blockIdx.x;
    const int t = threadIdx.x;
    const float4* w4 = reinterpret_cast<const float4*>(w_o + (long)n * D_MODEL);
    const float4* v4 = reinterpret_cast<const float4*>(b_v);
    float4 a = w4[t], b = w4[256 + t], va = v4[t], vb = v4[256 + t];
    float s = a.x*va.x + a.y*va.y + a.z*va.z + a.w*va.w
            + b.x*vb.x + b.y*vb.y + b.z*vb.z + b.w*vb.w;
    #pragma unroll
    for (int off = 32; off; off >>= 1) s += __shfl_xor(s, off);
    __shared__ float red[4];
    const int lane = t & 63, wid = t >> 6;
    if (lane == 0) red[wid] = s;
    __syncthreads();
    if (t == 0) b_c[n] = red[0] + red[1] + red[2] + red[3] + b_o[n];
}

// ---------------- BT-GEMM: C[m][n] = sum_k A[m][k]*B[n][k] ----------------
// A: bf16 [M][K] row-major, B: bf16 [N][K] row-major.
// EPI=0: store bf16 C[M][N].  EPI=1: store f32 C = acc + bias[col] + resid[row][col].
// 128x128 tile, BK=32, 4 waves (2x2 of 64x64), mfma_f32_16x16x32_bf16 (m97 structure).
template<int EPI>
__global__ __launch_bounds__(256, 2) void gemm_bt_128(
    const unsigned short* __restrict__ A, const unsigned short* __restrict__ B,
    void* __restrict__ Cout, const float* __restrict__ bias,
    const float* __restrict__ resid, int M, int N, int K)
{
    const int nBN = N >> 7;
    int wg = blockIdx.x;
    const int nwg = gridDim.x;
    // XCD-aware swizzle (bijective: nwg % 8 == 0 for all our launches)
    const int cpx = nwg >> 3;
    wg = (wg & 7) * cpx + (wg >> 3);
    const int bm = wg / nBN, bn = wg % nBN;

    const int t = threadIdx.x;
    const int lane = t & 63, wid = t >> 6;
    const int wr = wid >> 1, wc = wid & 1;

    __shared__ __align__(16) unsigned short Alds[128 * 32];
    __shared__ __align__(16) unsigned short Blds[128 * 32];

    f32x4 acc[4][4];
    #pragma unroll
    for (int i = 0; i < 4; i++)
        #pragma unroll
        for (int j = 0; j < 4; j++) acc[i][j] = (f32x4){0.f, 0.f, 0.f, 0.f};

    const long Abase = (long)bm * 128 * K;
    const long Bbase = (long)bn * 128 * K;
    const int ci0 = wid * 64 + lane;     // chunks [0,256)
    const int ci1 = 256 + ci0;           // chunks [256,512)
    const int r0 = ci0 >> 2, c0 = (ci0 & 3) * 8;
    const int r1 = ci1 >> 2, c1 = (ci1 & 3) * 8;

    const int arow = wr * 64 + (lane & 15);
    const int brow = wc * 64 + (lane & 15);
    const int koff = (lane >> 4) * 8;

    for (int k0 = 0; k0 < K; k0 += 32) {
        // stage A,B tiles (128x32 bf16 each) via async global->LDS, 16B/lane
        __builtin_amdgcn_global_load_lds(
            (const __attribute__((address_space(1))) void*)(A + Abase + (long)r0 * K + k0 + c0),
            (__attribute__((address_space(3))) void*)(Alds + wid * 512), 16, 0, 0);
        __builtin_amdgcn_global_load_lds(
            (const __attribute__((address_space(1))) void*)(A + Abase + (long)r1 * K + k0 + c1),
            (__attribute__((address_space(3))) void*)(Alds + 2048 + wid * 512), 16, 0, 0);
        __builtin_amdgcn_global_load_lds(
            (const __attribute__((address_space(1))) void*)(B + Bbase + (long)r0 * K + k0 + c0),
            (__attribute__((address_space(3))) void*)(Blds + wid * 512), 16, 0, 0);
        __builtin_amdgcn_global_load_lds(
            (const __attribute__((address_space(1))) void*)(B + Bbase + (long)r1 * K + k0 + c1),
            (__attribute__((address_space(3))) void*)(Blds + 2048 + wid * 512), 16, 0, 0);
        __syncthreads();   // drains vmcnt -> tiles resident

        bf16x8 af[4], bfr[4];
        #pragma unroll
        for (int m = 0; m < 4; m++)
            af[m] = *reinterpret_cast<const bf16x8*>(&Alds[(arow + m * 16) * 32 + koff]);
        #pragma unroll
        for (int n = 0; n < 4; n++)
            bfr[n] = *reinterpret_cast<const bf16x8*>(&Blds[(brow + n * 16) * 32 + koff]);
        #pragma unroll
        for (int m = 0; m < 4; m++)
            #pragma unroll
            for (int n = 0; n < 4; n++)
                acc[m][n] = __builtin_amdgcn_mfma_f32_16x16x32_bf16(af[m], bfr[n], acc[m][n], 0, 0, 0);
        __syncthreads();   // before next-tile overwrite
    }

    // C/D layout (m89 verified): col = lane&15, row = (lane>>4)*4 + reg
    const int crow0 = bm * 128 + wr * 64 + ((lane >> 4) << 2);
    const int ccol0 = bn * 128 + wc * 64 + (lane & 15);
    if (EPI == 0) {
        unsigned short* C = (unsigned short*)Cout;
        #pragma unroll
        for (int m = 0; m < 4; m++)
            #pragma unroll
            for (int j = 0; j < 4; j++) {
                const long r = crow0 + m * 16 + j;
                #pragma unroll
                for (int n = 0; n < 4; n++)
                    C[r * N + ccol0 + n * 16] = f2bf(acc[m][n][j]);
            }
    } else {
        float* C = (float*)Cout;
        #pragma unroll
        for (int m = 0; m < 4; m++)
            #pragma unroll
            for (int j = 0; j < 4; j++) {
                const long r = crow0 + m * 16 + j;
                const float* resrow = resid + r * N;
                float* crow = C + r * N;
                #pragma unroll
                for (int n = 0; n < 4; n++) {
                    const int c = ccol0 + n * 16;
                    crow[c] = acc[m][n][j] + bias[c] + resrow[c];
                }
            }
    }
}

extern "C" void kernel_launch(void* const* d_in, const int* in_sizes, int n_in,
                              void* d_out, int out_size, void* d_ws, size_t ws_size,
                              hipStream_t stream) {
    // setup_inputs order: x, w_q, b_q, w_k, b_k, w_v, b_v, w_o, b_o, ln_gamma, ln_beta
    const float* x     = (const float*)d_in[0];
    const float* w_v   = (const float*)d_in[5];
    const float* b_v   = (const float*)d_in[6];
    const float* w_o   = (const float*)d_in[7];
    const float* b_o   = (const float*)d_in[8];
    const float* gamma = (const float*)d_in[9];
    const float* beta  = (const float*)d_in[10];
    float* out = (float*)d_out;

    // workspace layout (all 256B-aligned)
    char* ws = (char*)d_ws;
    unsigned short* h   = (unsigned short*)(ws);                              // 16384*2048*2 = 64 MiB
    unsigned short* wvT = (unsigned short*)(ws + 67108864L);                  // 8 MiB
    unsigned short* woB = (unsigned short*)(ws + 67108864L + 8388608L);       // 8 MiB
    unsigned short* Wc  = (unsigned short*)(ws + 67108864L + 2 * 8388608L);   // 8 MiB
    float*          b_c = (float*)(ws + 67108864L + 3 * 8388608L);            // 8 KiB

    // 1) h = LN(x) in bf16
    ln_kernel<<<N_BATCH, 256, 0, stream>>>(x, gamma, beta, h);
    // 2) wvT[k][j] = bf16(w_v[j][k])
    transpose_f32_to_bf16<<<(D_MODEL / 32) * (D_MODEL / 32), 256, 0, stream>>>(w_v, wvT, D_MODEL);
    // 3) woB = bf16(w_o)
    convert_bf16<<<(D_MODEL * (long)D_MODEL) / (256 * 8), 256, 0, stream>>>(w_o, woB, (long)D_MODEL * D_MODEL);
    // 4) b_c = w_o @ b_v + b_o (fp32)
    bias_combine<<<D_MODEL, 256, 0, stream>>>(w_o, b_v, b_o, b_c);
    // 5) Wc[n][k] = sum_j w_o[n][j] * w_v[j][k]   (C = woB · wvT^T, both [2048][2048])
    gemm_bt_128<0><<<(D_MODEL / 128) * (D_MODEL / 128), 256, 0, stream>>>(
        woB, wvT, (void*)Wc, nullptr, nullptr, D_MODEL, D_MODEL, D_MODEL);
    // 6) out[b][n] = sum_k h[b][k] * Wc[n][k] + b_c[n] + x[b][n]
    gemm_bt_128<1><<<(N_BATCH / 128) * (D_MODEL / 128), 256, 0, stream>>>(
        h, Wc, (void*)out, b_c, x, N_BATCH, D_MODEL, D_MODEL);
}

// Round 2
// 259.973 us; speedup vs baseline: 1.0687x; 1.0687x over previous
//
#include <hip/hip_runtime.h>
#include <hip/hip_bf16.h>
#include <cstdint>

#define D_MODEL 2048
#define N_BATCH 16384

typedef __attribute__((ext_vector_type(8))) __bf16 bf16x8;
typedef __attribute__((ext_vector_type(4))) float f32x4;

__device__ __forceinline__ unsigned short f2bf(float f) {
    unsigned int u = __builtin_bit_cast(unsigned int, f);
    u += 0x7fffu + ((u >> 16) & 1u);
    return (unsigned short)(u >> 16);
}

// ---------------- LayerNorm: x fp32 [B][D] -> h bf16 [B][D] ----------------
__global__ __launch_bounds__(256) void ln_kernel(
    const float* __restrict__ x, const float* __restrict__ gamma,
    const float* __restrict__ beta, unsigned short* __restrict__ h)
{
    const int row = blockIdx.x;
    const int t = threadIdx.x;
    const float4* x4 = reinterpret_cast<const float4*>(x + (long)row * D_MODEL);
    float4 a = x4[t];
    float4 b = x4[256 + t];
    float s  = a.x + a.y + a.z + a.w + b.x + b.y + b.z + b.w;
    float ss = a.x*a.x + a.y*a.y + a.z*a.z + a.w*a.w
             + b.x*b.x + b.y*b.y + b.z*b.z + b.w*b.w;
    #pragma unroll
    for (int off = 32; off; off >>= 1) {
        s  += __shfl_xor(s, off);
        ss += __shfl_xor(ss, off);
    }
    __shared__ float red[8];
    const int lane = t & 63, wid = t >> 6;
    if (lane == 0) { red[wid*2] = s; red[wid*2+1] = ss; }
    __syncthreads();
    s  = red[0] + red[2] + red[4] + red[6];
    ss = red[1] + red[3] + red[5] + red[7];
    const float mean = s * (1.0f / D_MODEL);
    const float var  = ss * (1.0f / D_MODEL) - mean * mean;
    const float inv  = rsqrtf(var + 1e-5f);

    const float4* g4  = reinterpret_cast<const float4*>(gamma);
    const float4* be4 = reinterpret_cast<const float4*>(beta);
    ushort4* h4 = reinterpret_cast<ushort4*>(h + (long)row * D_MODEL);
    {
        float4 g = g4[t], be = be4[t];
        ushort4 o;
        o.x = f2bf((a.x - mean) * inv * g.x + be.x);
        o.y = f2bf((a.y - mean) * inv * g.y + be.y);
        o.z = f2bf((a.z - mean) * inv * g.z + be.z);
        o.w = f2bf((a.w - mean) * inv * g.w + be.w);
        h4[t] = o;
    }
    {
        float4 g = g4[256 + t], be = be4[256 + t];
        ushort4 o;
        o.x = f2bf((b.x - mean) * inv * g.x + be.x);
        o.y = f2bf((b.y - mean) * inv * g.y + be.y);
        o.z = f2bf((b.z - mean) * inv * g.z + be.z);
        o.w = f2bf((b.w - mean) * inv * g.w + be.w);
        h4[256 + t] = o;
    }
}

// ------------- transpose + convert: out[k][j] = bf16(in[j][k]) -------------
__global__ __launch_bounds__(256) void transpose_f32_to_bf16(
    const float* __restrict__ in, unsigned short* __restrict__ out, int Dm)
{
    __shared__ float tile[32][33];
    const int nb = Dm >> 5;
    const int k0 = (blockIdx.x % nb) * 32;
    const int j0 = (blockIdx.x / nb) * 32;
    const int tx = threadIdx.x & 31, ty0 = threadIdx.x >> 5;
    #pragma unroll
    for (int i = 0; i < 32; i += 8) {
        int j = ty0 + i;
        tile[j][tx] = in[(long)(j0 + j) * Dm + k0 + tx];
    }
    __syncthreads();
    #pragma unroll
    for (int i = 0; i < 32; i += 8) {
        int kk = ty0 + i;
        out[(long)(k0 + kk) * Dm + j0 + tx] = f2bf(tile[tx][kk]);
    }
}

// ---------------- elementwise convert fp32 -> bf16 ----------------
__global__ __launch_bounds__(256) void convert_bf16(
    const float* __restrict__ in, unsigned short* __restrict__ out, long n)
{
    long i = ((long)blockIdx.x * 256 + threadIdx.x) * 8;
    if (i >= n) return;
    const float4* in4 = reinterpret_cast<const float4*>(in + i);
    float4 a = in4[0], b = in4[1];
    union { unsigned short u[8]; uint4 v; } o;
    o.u[0] = f2bf(a.x); o.u[1] = f2bf(a.y); o.u[2] = f2bf(a.z); o.u[3] = f2bf(a.w);
    o.u[4] = f2bf(b.x); o.u[5] = f2bf(b.y); o.u[6] = f2bf(b.z); o.u[7] = f2bf(b.w);
    *reinterpret_cast<uint4*>(out + i) = o.v;
}

// ---------------- b_c[n] = b_o[n] + sum_j w_o[n][j]*b_v[j] (fp32) ----------------
__global__ __launch_bounds__(256) void bias_combine(
    const float* __restrict__ w_o, const float* __restrict__ b_v,
    const float* __restrict__ b_o, float* __restrict__ b_c)
{
    const int n = blockIdx.x;
    const int t = threadIdx.x;
    const float4* w4 = reinterpret_cast<const float4*>(w_o + (long)n * D_MODEL);
    const float4* v4 = reinterpret_cast<const float4*>(b_v);
    float4 a = w4[t], b = w4[256 + t], va = v4[t], vb = v4[256 + t];
    float s = a.x*va.x + a.y*va.y + a.z*va.z + a.w*va.w
            + b.x*vb.x + b.y*vb.y + b.z*vb.z + b.w*vb.w;
    #pragma unroll
    for (int off = 32; off; off >>= 1) s += __shfl_xor(s, off);
    __shared__ float red[4];
    const int lane = t & 63, wid = t >> 6;
    if (lane == 0) red[wid] = s;
    __syncthreads();
    if (t == 0) b_c[n] = red[0] + red[1] + red[2] + red[3] + b_o[n];
}

// ---------------- small BT-GEMM (128x128 tile, m97 structure), bf16 out ----------------
__global__ __launch_bounds__(256, 2) void gemm_bt_128(
    const unsigned short* __restrict__ A, const unsigned short* __restrict__ B,
    unsigned short* __restrict__ C, int M, int N, int K)
{
    const int nBN = N >> 7;
    int wg = blockIdx.x;
    const int nwg = gridDim.x;
    const int cpx = nwg >> 3;
    wg = (wg & 7) * cpx + (wg >> 3);
    const int bm = wg / nBN, bn = wg % nBN;

    const int t = threadIdx.x;
    const int lane = t & 63, wid = t >> 6;
    const int wr = wid >> 1, wc = wid & 1;

    __shared__ __align__(16) unsigned short Alds[128 * 32];
    __shared__ __align__(16) unsigned short Blds[128 * 32];

    f32x4 acc[4][4];
    #pragma unroll
    for (int i = 0; i < 4; i++)
        #pragma unroll
        for (int j = 0; j < 4; j++) acc[i][j] = (f32x4){0.f, 0.f, 0.f, 0.f};

    const long Abase = (long)bm * 128 * K;
    const long Bbase = (long)bn * 128 * K;
    const int ci0 = wid * 64 + lane;
    const int ci1 = 256 + ci0;
    const int r0 = ci0 >> 2, c0 = (ci0 & 3) * 8;
    const int r1 = ci1 >> 2, c1 = (ci1 & 3) * 8;

    const int arow = wr * 64 + (lane & 15);
    const int brow = wc * 64 + (lane & 15);
    const int koff = (lane >> 4) * 8;

    for (int k0 = 0; k0 < K; k0 += 32) {
        __builtin_amdgcn_global_load_lds(
            (const __attribute__((address_space(1))) void*)(A + Abase + (long)r0 * K + k0 + c0),
            (__attribute__((address_space(3))) void*)(Alds + wid * 512), 16, 0, 0);
        __builtin_amdgcn_global_load_lds(
            (const __attribute__((address_space(1))) void*)(A + Abase + (long)r1 * K + k0 + c1),
            (__attribute__((address_space(3))) void*)(Alds + 2048 + wid * 512), 16, 0, 0);
        __builtin_amdgcn_global_load_lds(
            (const __attribute__((address_space(1))) void*)(B + Bbase + (long)r0 * K + k0 + c0),
            (__attribute__((address_space(3))) void*)(Blds + wid * 512), 16, 0, 0);
        __builtin_amdgcn_global_load_lds(
            (const __attribute__((address_space(1))) void*)(B + Bbase + (long)r1 * K + k0 + c1),
            (__attribute__((address_space(3))) void*)(Blds + 2048 + wid * 512), 16, 0, 0);
        __syncthreads();

        bf16x8 af[4], bfr[4];
        #pragma unroll
        for (int m = 0; m < 4; m++)
            af[m] = *reinterpret_cast<const bf16x8*>(&Alds[(arow + m * 16) * 32 + koff]);
        #pragma unroll
        for (int n = 0; n < 4; n++)
            bfr[n] = *reinterpret_cast<const bf16x8*>(&Blds[(brow + n * 16) * 32 + koff]);
        #pragma unroll
        for (int m = 0; m < 4; m++)
            #pragma unroll
            for (int n = 0; n < 4; n++)
                acc[m][n] = __builtin_amdgcn_mfma_f32_16x16x32_bf16(af[m], bfr[n], acc[m][n], 0, 0, 0);
        __syncthreads();
    }

    const int crow0 = bm * 128 + wr * 64 + ((lane >> 4) << 2);
    const int ccol0 = bn * 128 + wc * 64 + (lane & 15);
    #pragma unroll
    for (int m = 0; m < 4; m++)
        #pragma unroll
        for (int j = 0; j < 4; j++) {
            const long r = crow0 + m * 16 + j;
            #pragma unroll
            for (int n = 0; n < 4; n++)
                C[r * N + ccol0 + n * 16] = f2bf(acc[m][n][j]);
        }
}

// ============ big BT-GEMM: 256x256 tile, BK=64, 8 waves, phase-barriered ============
// C[m][n] = sum_k A[m][k]*B[n][k] + bias[n] + resid[m][n], fp32 out.
// LDS: 2 buffers x (A 256x64 + B 256x64) bf16, swizzled slot(r,kc)=r*8+(kc^(r&7)).
// Stage: linear global_load_lds dest + inverse-swizzled global source (rule 21).
// Per K-tile: 4 phases (C-quadrants), raw s_barrier (no vmcnt drain), setprio
// around MFMA clusters; all 8 next-tile stages issued at phase 0, vmcnt(0) at
// end of phase 3 (~3 phases of MFMA hide the load latency).
#define BAR() __builtin_amdgcn_s_barrier()
#define LGKM0() do { asm volatile("s_waitcnt lgkmcnt(0)" ::: "memory"); \
                     __builtin_amdgcn_sched_barrier(0); } while (0)

__global__ __launch_bounds__(512, 2) void gemm_bt_256(
    const unsigned short* __restrict__ A, const unsigned short* __restrict__ B,
    float* __restrict__ C, const float* __restrict__ bias,
    const float* __restrict__ resid, int M, int N, int K)
{
    __shared__ __align__(16) char lds[131072];   // 128 KiB: [buf][A 32K | B 32K]

    const int nBN = N >> 8;
    int wg = blockIdx.x;
    const int nwg = gridDim.x;
    const int cpx = nwg >> 3;           // nwg % 8 == 0 (512)
    wg = (wg & 7) * cpx + (wg >> 3);
    const int bm = wg / nBN, bn = wg % nBN;

    const int t = threadIdx.x;
    const int lane = t & 63, wid = t >> 6;
    const int wr = wid >> 2;            // 0..1 : wave row (128 rows)
    const int wcn = wid & 3;            // 0..3 : wave col (64 cols)

    // --- staging addresses: thread t covers LDS slot (q*512 + t) of each quarter
    const int sr = t >> 3;                       // row within 64-row quarter
    const int sc8 = (((t & 7) ^ (sr & 7)) * 8);  // inverse-swizzled k element offset
    const unsigned short* aq[4];
    const unsigned short* bq[4];
    {
        const long Ag = (long)bm * 256 * K;
        const long Bg = (long)bn * 256 * K;
        #pragma unroll
        for (int q = 0; q < 4; q++) {
            aq[q] = A + Ag + (long)(q * 64 + sr) * K + sc8;
            bq[q] = B + Bg + (long)(q * 64 + sr) * K + sc8;
        }
    }

#define STAGE(d) do { \
        const int dstA = (d) * 65536 + wid * 1024; \
        _Pragma("unroll") \
        for (int q = 0; q < 4; q++) { \
            __builtin_amdgcn_global_load_lds( \
                (const __attribute__((address_space(1))) void*)aq[q], \
                (__attribute__((address_space(3))) void*)(lds + dstA + q * 8192), 16, 0, 0); \
            __builtin_amdgcn_global_load_lds( \
                (const __attribute__((address_space(1))) void*)bq[q], \
                (__attribute__((address_space(3))) void*)(lds + dstA + 32768 + q * 8192), 16, 0, 0); \
            aq[q] += 64; bq[q] += 64; \
        } \
    } while (0)

    // --- ds_read offsets (swizzled)
    const int l15 = lane & 15, l4 = lane >> 4, l7 = lane & 7;
    const int swzk[2] = { ((0 + l4) ^ l7) * 16, ((4 + l4) ^ l7) * 16 };
    const int a_rb = (wr * 128 + l15) * 128;   // row byte base within A buf
    const int b_rb = (wcn * 64 + l15) * 128;   // row byte base within B buf

    f32x4 acc[8][4];
    #pragma unroll
    for (int i = 0; i < 8; i++)
        #pragma unroll
        for (int j = 0; j < 4; j++) acc[i][j] = (f32x4){0.f, 0.f, 0.f, 0.f};

#define RD_A(mh) \
    _Pragma("unroll") for (int mi = 0; mi < 4; mi++) \
    _Pragma("unroll") for (int kk = 0; kk < 2; kk++) \
        af[mi][kk] = *reinterpret_cast<const bf16x8*>( \
            lds + ab + a_rb + ((mh) * 4 + mi) * 2048 + swzk[kk]);
#define RD_B(nh) \
    _Pragma("unroll") for (int ni = 0; ni < 2; ni++) \
    _Pragma("unroll") for (int kk = 0; kk < 2; kk++) \
        bfr[ni][kk] = *reinterpret_cast<const bf16x8*>( \
            lds + bb + b_rb + ((nh) * 2 + ni) * 2048 + swzk[kk]);
#define MFMA_Q(mh, nh) \
    _Pragma("unroll") for (int mi = 0; mi < 4; mi++) \
    _Pragma("unroll") for (int ni = 0; ni < 2; ni++) \
    _Pragma("unroll") for (int kk = 0; kk < 2; kk++) \
        acc[(mh) * 4 + mi][(nh) * 2 + ni] = __builtin_amdgcn_mfma_f32_16x16x32_bf16( \
            af[mi][kk], bfr[ni][kk], acc[(mh) * 4 + mi][(nh) * 2 + ni], 0, 0, 0);

    // --- prologue: stage tile 0 into buf 0
    STAGE(0);
    asm volatile("s_waitcnt vmcnt(0)" ::: "memory");
    __syncthreads();

    const int nt = K >> 6;
    int c = 0;
    for (int kt = 0; kt < nt; ++kt) {
        const int ab = c * 65536;
        const int bb = ab + 32768;
        const bool next = (kt + 1 < nt);
        bf16x8 af[4][2], bfr[2][2];

        // phase 0: quadrant (0,0); issue all next-tile stages
        RD_A(0); RD_B(0);
        if (next) STAGE(c ^ 1);
        BAR(); LGKM0();
        __builtin_amdgcn_s_setprio(1); MFMA_Q(0, 0); __builtin_amdgcn_s_setprio(0);
        BAR();
        // phase 1: quadrant (0,1)
        RD_B(1);
        BAR(); LGKM0();
        __builtin_amdgcn_s_setprio(1); MFMA_Q(0, 1); __builtin_amdgcn_s_setprio(0);
        BAR();
        // phase 2: quadrant (1,0)
        RD_A(1); RD_B(0);
        BAR(); LGKM0();
        __builtin_amdgcn_s_setprio(1); MFMA_Q(1, 0); __builtin_amdgcn_s_setprio(0);
        BAR();
        // phase 3: quadrant (1,1)
        RD_B(1);
        BAR(); LGKM0();
        __builtin_amdgcn_s_setprio(1); MFMA_Q(1, 1); __builtin_amdgcn_s_setprio(0);
        if (next) { asm volatile("s_waitcnt vmcnt(0)" ::: "memory"); }
        BAR();
        c ^= 1;
    }

    // --- epilogue: C = acc + bias[col] + resid[row][col]
    const int crow0 = bm * 256 + wr * 128 + l4 * 4;
    const int ccol0 = bn * 256 + wcn * 64 + l15;
    #pragma unroll
    for (int m = 0; m < 8; m++)
        #pragma unroll
        for (int j = 0; j < 4; j++) {
            const long r = crow0 + m * 16 + j;
            float* crow = C + r * N;
            const float* rrow = resid + r * N;
            #pragma unroll
            for (int n = 0; n < 4; n++) {
                const int col = ccol0 + n * 16;
                crow[col] = acc[m][n][j] + bias[col] + rrow[col];
            }
        }
#undef STAGE
#undef RD_A
#undef RD_B
#undef MFMA_Q
}

extern "C" void kernel_launch(void* const* d_in, const int* in_sizes, int n_in,
                              void* d_out, int out_size, void* d_ws, size_t ws_size,
                              hipStream_t stream) {
    // setup_inputs order: x, w_q, b_q, w_k, b_k, w_v, b_v, w_o, b_o, ln_gamma, ln_beta
    const float* x     = (const float*)d_in[0];
    const float* w_v   = (const float*)d_in[5];
    const float* b_v   = (const float*)d_in[6];
    const float* w_o   = (const float*)d_in[7];
    const float* b_o   = (const float*)d_in[8];
    const float* gamma = (const float*)d_in[9];
    const float* beta  = (const float*)d_in[10];
    float* out = (float*)d_out;

    char* ws = (char*)d_ws;
    unsigned short* h   = (unsigned short*)(ws);                              // 64 MiB
    unsigned short* wvT = (unsigned short*)(ws + 67108864L);                  // 8 MiB
    unsigned short* woB = (unsigned short*)(ws + 67108864L + 8388608L);       // 8 MiB
    unsigned short* Wc  = (unsigned short*)(ws + 67108864L + 2 * 8388608L);   // 8 MiB
    float*          b_c = (float*)(ws + 67108864L + 3 * 8388608L);            // 8 KiB

    // 1) h = LN(x) in bf16
    ln_kernel<<<N_BATCH, 256, 0, stream>>>(x, gamma, beta, h);
    // 2) wvT[k][j] = bf16(w_v[j][k])
    transpose_f32_to_bf16<<<(D_MODEL / 32) * (D_MODEL / 32), 256, 0, stream>>>(w_v, wvT, D_MODEL);
    // 3) woB = bf16(w_o)
    convert_bf16<<<(D_MODEL * (long)D_MODEL) / (256 * 8), 256, 0, stream>>>(w_o, woB, (long)D_MODEL * D_MODEL);
    // 4) b_c = w_o @ b_v + b_o (fp32)
    bias_combine<<<D_MODEL, 256, 0, stream>>>(w_o, b_v, b_o, b_c);
    // 5) Wc[n][k] = sum_j w_o[n][j] * w_v[j][k]
    gemm_bt_128<<<(D_MODEL / 128) * (D_MODEL / 128), 256, 0, stream>>>(
        woB, wvT, Wc, D_MODEL, D_MODEL, D_MODEL);
    // 6) out[b][n] = sum_k h[b][k] * Wc[n][k] + b_c[n] + x[b][n]
    gemm_bt_256<<<(N_BATCH / 256) * (D_MODEL / 256), 512, 0, stream>>>(
        h, Wc, out, b_c, x, N_BATCH, D_MODEL, D_MODEL);
}

// Round 3
// 254.052 us; speedup vs baseline: 1.0936x; 1.0233x over previous
//
#include <hip/hip_runtime.h>
#include <hip/hip_bf16.h>
#include <cstdint>

#define D_MODEL 2048
#define N_BATCH 16384

typedef __attribute__((ext_vector_type(8))) __bf16 bf16x8;
typedef __attribute__((ext_vector_type(4))) float f32x4;

__device__ __forceinline__ unsigned short f2bf(float f) {
    unsigned int u = __builtin_bit_cast(unsigned int, f);
    u += 0x7fffu + ((u >> 16) & 1u);
    return (unsigned short)(u >> 16);
}

// ---------------- LayerNorm: x fp32 [B][D] -> h bf16 [B][D] ----------------
__global__ __launch_bounds__(256) void ln_kernel(
    const float* __restrict__ x, const float* __restrict__ gamma,
    const float* __restrict__ beta, unsigned short* __restrict__ h)
{
    const int row = blockIdx.x;
    const int t = threadIdx.x;
    const float4* x4 = reinterpret_cast<const float4*>(x + (long)row * D_MODEL);
    float4 a = x4[t];
    float4 b = x4[256 + t];
    float s  = a.x + a.y + a.z + a.w + b.x + b.y + b.z + b.w;
    float ss = a.x*a.x + a.y*a.y + a.z*a.z + a.w*a.w
             + b.x*b.x + b.y*b.y + b.z*b.z + b.w*b.w;
    #pragma unroll
    for (int off = 32; off; off >>= 1) {
        s  += __shfl_xor(s, off);
        ss += __shfl_xor(ss, off);
    }
    __shared__ float red[8];
    const int lane = t & 63, wid = t >> 6;
    if (lane == 0) { red[wid*2] = s; red[wid*2+1] = ss; }
    __syncthreads();
    s  = red[0] + red[2] + red[4] + red[6];
    ss = red[1] + red[3] + red[5] + red[7];
    const float mean = s * (1.0f / D_MODEL);
    const float var  = ss * (1.0f / D_MODEL) - mean * mean;
    const float inv  = rsqrtf(var + 1e-5f);

    const float4* g4  = reinterpret_cast<const float4*>(gamma);
    const float4* be4 = reinterpret_cast<const float4*>(beta);
    ushort4* h4 = reinterpret_cast<ushort4*>(h + (long)row * D_MODEL);
    {
        float4 g = g4[t], be = be4[t];
        ushort4 o;
        o.x = f2bf((a.x - mean) * inv * g.x + be.x);
        o.y = f2bf((a.y - mean) * inv * g.y + be.y);
        o.z = f2bf((a.z - mean) * inv * g.z + be.z);
        o.w = f2bf((a.w - mean) * inv * g.w + be.w);
        h4[t] = o;
    }
    {
        float4 g = g4[256 + t], be = be4[256 + t];
        ushort4 o;
        o.x = f2bf((b.x - mean) * inv * g.x + be.x);
        o.y = f2bf((b.y - mean) * inv * g.y + be.y);
        o.z = f2bf((b.z - mean) * inv * g.z + be.z);
        o.w = f2bf((b.w - mean) * inv * g.w + be.w);
        h4[256 + t] = o;
    }
}

// ------------- transpose + convert: out[k][j] = bf16(in[j][k]) -------------
__global__ __launch_bounds__(256) void transpose_f32_to_bf16(
    const float* __restrict__ in, unsigned short* __restrict__ out, int Dm)
{
    __shared__ float tile[32][33];
    const int nb = Dm >> 5;
    const int k0 = (blockIdx.x % nb) * 32;
    const int j0 = (blockIdx.x / nb) * 32;
    const int tx = threadIdx.x & 31, ty0 = threadIdx.x >> 5;
    #pragma unroll
    for (int i = 0; i < 32; i += 8) {
        int j = ty0 + i;
        tile[j][tx] = in[(long)(j0 + j) * Dm + k0 + tx];
    }
    __syncthreads();
    #pragma unroll
    for (int i = 0; i < 32; i += 8) {
        int kk = ty0 + i;
        out[(long)(k0 + kk) * Dm + j0 + tx] = f2bf(tile[tx][kk]);
    }
}

// ---------------- elementwise convert fp32 -> bf16 ----------------
__global__ __launch_bounds__(256) void convert_bf16(
    const float* __restrict__ in, unsigned short* __restrict__ out, long n)
{
    long i = ((long)blockIdx.x * 256 + threadIdx.x) * 8;
    if (i >= n) return;
    const float4* in4 = reinterpret_cast<const float4*>(in + i);
    float4 a = in4[0], b = in4[1];
    union { unsigned short u[8]; uint4 v; } o;
    o.u[0] = f2bf(a.x); o.u[1] = f2bf(a.y); o.u[2] = f2bf(a.z); o.u[3] = f2bf(a.w);
    o.u[4] = f2bf(b.x); o.u[5] = f2bf(b.y); o.u[6] = f2bf(b.z); o.u[7] = f2bf(b.w);
    *reinterpret_cast<uint4*>(out + i) = o.v;
}

// ---------------- b_c[n] = b_o[n] + sum_j w_o[n][j]*b_v[j] (fp32) ----------------
__global__ __launch_bounds__(256) void bias_combine(
    const float* __restrict__ w_o, const float* __restrict__ b_v,
    const float* __restrict__ b_o, float* __restrict__ b_c)
{
    const int n = blockIdx.x;
    const int t = threadIdx.x;
    const float4* w4 = reinterpret_cast<const float4*>(w_o + (long)n * D_MODEL);
    const float4* v4 = reinterpret_cast<const float4*>(b_v);
    float4 a = w4[t], b = w4[256 + t], va = v4[t], vb = v4[256 + t];
    float s = a.x*va.x + a.y*va.y + a.z*va.z + a.w*va.w
            + b.x*vb.x + b.y*vb.y + b.z*vb.z + b.w*vb.w;
    #pragma unroll
    for (int off = 32; off; off >>= 1) s += __shfl_xor(s, off);
    __shared__ float red[4];
    const int lane = t & 63, wid = t >> 6;
    if (lane == 0) red[wid] = s;
    __syncthreads();
    if (t == 0) b_c[n] = red[0] + red[1] + red[2] + red[3] + b_o[n];
}

// ---------------- small BT-GEMM (128x128 tile, m97 structure), bf16 out ----------------
__global__ __launch_bounds__(256, 2) void gemm_bt_128(
    const unsigned short* __restrict__ A, const unsigned short* __restrict__ B,
    unsigned short* __restrict__ C, int M, int N, int K)
{
    const int nBN = N >> 7;
    int wg = blockIdx.x;
    const int nwg = gridDim.x;
    const int cpx = nwg >> 3;
    wg = (wg & 7) * cpx + (wg >> 3);
    const int bm = wg / nBN, bn = wg % nBN;

    const int t = threadIdx.x;
    const int lane = t & 63, wid = t >> 6;
    const int wr = wid >> 1, wc = wid & 1;

    __shared__ __align__(16) unsigned short Alds[128 * 32];
    __shared__ __align__(16) unsigned short Blds[128 * 32];

    f32x4 acc[4][4];
    #pragma unroll
    for (int i = 0; i < 4; i++)
        #pragma unroll
        for (int j = 0; j < 4; j++) acc[i][j] = (f32x4){0.f, 0.f, 0.f, 0.f};

    const long Abase = (long)bm * 128 * K;
    const long Bbase = (long)bn * 128 * K;
    const int ci0 = wid * 64 + lane;
    const int ci1 = 256 + ci0;
    const int r0 = ci0 >> 2, c0 = (ci0 & 3) * 8;
    const int r1 = ci1 >> 2, c1 = (ci1 & 3) * 8;

    const int arow = wr * 64 + (lane & 15);
    const int brow = wc * 64 + (lane & 15);
    const int koff = (lane >> 4) * 8;

    for (int k0 = 0; k0 < K; k0 += 32) {
        __builtin_amdgcn_global_load_lds(
            (const __attribute__((address_space(1))) void*)(A + Abase + (long)r0 * K + k0 + c0),
            (__attribute__((address_space(3))) void*)(Alds + wid * 512), 16, 0, 0);
        __builtin_amdgcn_global_load_lds(
            (const __attribute__((address_space(1))) void*)(A + Abase + (long)r1 * K + k0 + c1),
            (__attribute__((address_space(3))) void*)(Alds + 2048 + wid * 512), 16, 0, 0);
        __builtin_amdgcn_global_load_lds(
            (const __attribute__((address_space(1))) void*)(B + Bbase + (long)r0 * K + k0 + c0),
            (__attribute__((address_space(3))) void*)(Blds + wid * 512), 16, 0, 0);
        __builtin_amdgcn_global_load_lds(
            (const __attribute__((address_space(1))) void*)(B + Bbase + (long)r1 * K + k0 + c1),
            (__attribute__((address_space(3))) void*)(Blds + 2048 + wid * 512), 16, 0, 0);
        __syncthreads();

        bf16x8 af[4], bfr[4];
        #pragma unroll
        for (int m = 0; m < 4; m++)
            af[m] = *reinterpret_cast<const bf16x8*>(&Alds[(arow + m * 16) * 32 + koff]);
        #pragma unroll
        for (int n = 0; n < 4; n++)
            bfr[n] = *reinterpret_cast<const bf16x8*>(&Blds[(brow + n * 16) * 32 + koff]);
        #pragma unroll
        for (int m = 0; m < 4; m++)
            #pragma unroll
            for (int n = 0; n < 4; n++)
                acc[m][n] = __builtin_amdgcn_mfma_f32_16x16x32_bf16(af[m], bfr[n], acc[m][n], 0, 0, 0);
        __syncthreads();
    }

    const int crow0 = bm * 128 + wr * 64 + ((lane >> 4) << 2);
    const int ccol0 = bn * 128 + wc * 64 + (lane & 15);
    #pragma unroll
    for (int m = 0; m < 4; m++)
        #pragma unroll
        for (int j = 0; j < 4; j++) {
            const long r = crow0 + m * 16 + j;
            #pragma unroll
            for (int n = 0; n < 4; n++)
                C[r * N + ccol0 + n * 16] = f2bf(acc[m][n][j]);
        }
}

// ======== big BT-GEMM: 256x256 tile, BK=32, 8 waves, counted-vmcnt pipeline ========
// C[m][n] = sum_k A[m][k]*B[n][k] + bias[n] + resid[m][n], fp32 out.
// LDS: 4 buffers x (A 256x32 | B 256x32) bf16 = 4 x 32 KiB. Stage 3 tiles ahead.
// Swizzle (rule 21, both sides): LDS slot (r, c) holds global k-chunk c^(r&3);
// staging uses linear gload_lds dest + inverse-swizzled global source; ds_read
// applies the same XOR. Lanes 0-15 of a frag read then spread across 8
// bank-quads -> 2-way = free.
// Per tile: 2 phases (16 MFMA each, setprio-wrapped); phase 0 stages A(kt+3),
// phase 1 stages B(kt+3). Counted s_waitcnt vmcnt(8) at tile start (2 newer
// tiles x 4 loads stay in flight); tail drains 8->4->0. Never drain-0 mid-loop.
__global__ __launch_bounds__(512, 2) void gemm_bt_256(
    const unsigned short* __restrict__ A, const unsigned short* __restrict__ B,
    float* __restrict__ C, const float* __restrict__ bias,
    const float* __restrict__ resid, int M, int N, int K)
{
    __shared__ __align__(16) char lds[131072];   // 4 x [A 16K | B 16K]

    const int nBN = N >> 8;
    int wg = blockIdx.x;
    const int cpx = gridDim.x >> 3;     // nwg % 8 == 0 (512)
    wg = (wg & 7) * cpx + (wg >> 3);
    const int bm = wg / nBN, bn = wg % nBN;

    const int t = threadIdx.x;
    const int lane = t & 63, wid = t >> 6;
    const int wr = wid >> 2;            // 0..1 : wave row (128 rows)
    const int wcn = wid & 3;            // 0..3 : wave col (64 cols)

    // staging source (inverse-swizzled): thread t covers LDS slot (r_lo, t&3)
    const int r_lo = t >> 2, cch = t & 3;
    const int schunk = (cch ^ (r_lo & 3)) * 8;   // element offset of source chunk
    const unsigned short* sA0 = A + (long)(bm * 256 + r_lo) * K + schunk;
    const unsigned short* sA1 = sA0 + (long)128 * K;
    const unsigned short* sB0 = B + (long)(bn * 256 + r_lo) * K + schunk;
    const unsigned short* sB1 = sB0 + (long)128 * K;

#define STAGE_A(d) do { \
    __builtin_amdgcn_global_load_lds((const __attribute__((address_space(1))) void*)sA0, \
        (__attribute__((address_space(3))) void*)(lds + (d) * 32768 + wid * 1024), 16, 0, 0); \
    __builtin_amdgcn_global_load_lds((const __attribute__((address_space(1))) void*)sA1, \
        (__attribute__((address_space(3))) void*)(lds + (d) * 32768 + 8192 + wid * 1024), 16, 0, 0); \
    sA0 += 32; sA1 += 32; } while (0)
#define STAGE_B(d) do { \
    __builtin_amdgcn_global_load_lds((const __attribute__((address_space(1))) void*)sB0, \
        (__attribute__((address_space(3))) void*)(lds + (d) * 32768 + 16384 + wid * 1024), 16, 0, 0); \
    __builtin_amdgcn_global_load_lds((const __attribute__((address_space(1))) void*)sB1, \
        (__attribute__((address_space(3))) void*)(lds + (d) * 32768 + 24576 + wid * 1024), 16, 0, 0); \
    sB0 += 32; sB1 += 32; } while (0)

    // ds_read addressing (swizzled): row stride 64 B, chunk = (lane>>4) ^ (row&3)
    const int l15 = lane & 15, l4 = lane >> 4;
    const int koffb = ((l4 ^ (l15 & 3)) << 4);
    const int aRowB = (wr * 128 + l15) * 64 + koffb;           // + m*1024 (+4096 for mh=1)
    const int bRowB = 16384 + (wcn * 64 + l15) * 64 + koffb;   // + n*1024

    f32x4 acc[8][4];
    #pragma unroll
    for (int i = 0; i < 8; i++)
        #pragma unroll
        for (int j = 0; j < 4; j++) acc[i][j] = (f32x4){0.f, 0.f, 0.f, 0.f};

    const int nt = K >> 5;              // 64 tiles
    // prologue: stage tiles 0,1,2 (A before B per tile, matching loop order)
    STAGE_A(0); STAGE_B(0);
    STAGE_A(1); STAGE_B(1);
    STAGE_A(2); STAGE_B(2);

    for (int kt = 0; kt < nt; ++kt) {
        const int bufb = (kt & 3) * 32768;
        const int slack = nt - 1 - kt;
        // counted wait: keep 4 loads per not-yet-needed tile in flight
        if (slack >= 2)      asm volatile("s_waitcnt vmcnt(8)" ::: "memory");
        else if (slack == 1) asm volatile("s_waitcnt vmcnt(4)" ::: "memory");
        else                 asm volatile("s_waitcnt vmcnt(0)" ::: "memory");
        __builtin_amdgcn_s_barrier();
        __builtin_amdgcn_sched_barrier(0);

        bf16x8 af[4], bfr[4];
        #pragma unroll
        for (int n = 0; n < 4; n++)
            bfr[n] = *reinterpret_cast<const bf16x8*>(lds + bufb + bRowB + n * 1024);
        #pragma unroll
        for (int m = 0; m < 4; m++)
            af[m] = *reinterpret_cast<const bf16x8*>(lds + bufb + aRowB + m * 1024);
        if (kt + 3 < nt) STAGE_A((kt + 3) & 3);
        __builtin_amdgcn_s_setprio(1);
        #pragma unroll
        for (int m = 0; m < 4; m++)
            #pragma unroll
            for (int n = 0; n < 4; n++)
                acc[m][n] = __builtin_amdgcn_mfma_f32_16x16x32_bf16(af[m], bfr[n], acc[m][n], 0, 0, 0);
        __builtin_amdgcn_s_setprio(0);

        __builtin_amdgcn_s_barrier();
        __builtin_amdgcn_sched_barrier(0);

        #pragma unroll
        for (int m = 0; m < 4; m++)
            af[m] = *reinterpret_cast<const bf16x8*>(lds + bufb + aRowB + 4096 + m * 1024);
        if (kt + 3 < nt) STAGE_B((kt + 3) & 3);
        __builtin_amdgcn_s_setprio(1);
        #pragma unroll
        for (int m = 0; m < 4; m++)
            #pragma unroll
            for (int n = 0; n < 4; n++)
                acc[4 + m][n] = __builtin_amdgcn_mfma_f32_16x16x32_bf16(af[m], bfr[n], acc[4 + m][n], 0, 0, 0);
        __builtin_amdgcn_s_setprio(0);
    }
#undef STAGE_A
#undef STAGE_B

    // epilogue: C = acc + bias[col] + resid[row][col]
    const int crow0 = bm * 256 + wr * 128 + l4 * 4;
    const int ccol0 = bn * 256 + wcn * 64 + l15;
    #pragma unroll
    for (int m = 0; m < 8; m++)
        #pragma unroll
        for (int j = 0; j < 4; j++) {
            const long r = crow0 + m * 16 + j;
            float* crow = C + r * N;
            const float* rrow = resid + r * N;
            #pragma unroll
            for (int n = 0; n < 4; n++) {
                const int col = ccol0 + n * 16;
                crow[col] = acc[m][n][j] + bias[col] + rrow[col];
            }
        }
}

extern "C" void kernel_launch(void* const* d_in, const int* in_sizes, int n_in,
                              void* d_out, int out_size, void* d_ws, size_t ws_size,
                              hipStream_t stream) {
    // setup_inputs order: x, w_q, b_q, w_k, b_k, w_v, b_v, w_o, b_o, ln_gamma, ln_beta
    const float* x     = (const float*)d_in[0];
    const float* w_v   = (const float*)d_in[5];
    const float* b_v   = (const float*)d_in[6];
    const float* w_o   = (const float*)d_in[7];
    const float* b_o   = (const float*)d_in[8];
    const float* gamma = (const float*)d_in[9];
    const float* beta  = (const float*)d_in[10];
    float* out = (float*)d_out;

    char* ws = (char*)d_ws;
    unsigned short* h   = (unsigned short*)(ws);                              // 64 MiB
    unsigned short* wvT = (unsigned short*)(ws + 67108864L);                  // 8 MiB
    unsigned short* woB = (unsigned short*)(ws + 67108864L + 8388608L);       // 8 MiB
    unsigned short* Wc  = (unsigned short*)(ws + 67108864L + 2 * 8388608L);   // 8 MiB
    float*          b_c = (float*)(ws + 67108864L + 3 * 8388608L);            // 8 KiB

    // 1) h = LN(x) in bf16
    ln_kernel<<<N_BATCH, 256, 0, stream>>>(x, gamma, beta, h);
    // 2) wvT[k][j] = bf16(w_v[j][k])
    transpose_f32_to_bf16<<<(D_MODEL / 32) * (D_MODEL / 32), 256, 0, stream>>>(w_v, wvT, D_MODEL);
    // 3) woB = bf16(w_o)
    convert_bf16<<<(D_MODEL * (long)D_MODEL) / (256 * 8), 256, 0, stream>>>(w_o, woB, (long)D_MODEL * D_MODEL);
    // 4) b_c = w_o @ b_v + b_o (fp32)
    bias_combine<<<D_MODEL, 256, 0, stream>>>(w_o, b_v, b_o, b_c);
    // 5) Wc[n][k] = sum_j w_o[n][j] * w_v[j][k]
    gemm_bt_128<<<(D_MODEL / 128) * (D_MODEL / 128), 256, 0, stream>>>(
        woB, wvT, Wc, D_MODEL, D_MODEL, D_MODEL);
    // 6) out[b][n] = sum_k h[b][k] * Wc[n][k] + b_c[n] + x[b][n]
    gemm_bt_256<<<(N_BATCH / 256) * (D_MODEL / 256), 512, 0, stream>>>(
        h, Wc, out, b_c, x, N_BATCH, D_MODEL, D_MODEL);
}

// Round 4
// 251.227 us; speedup vs baseline: 1.1059x; 1.0112x over previous
//
#include <hip/hip_runtime.h>
#include <hip/hip_bf16.h>
#include <cstdint>

#define D_MODEL 2048
#define N_BATCH 16384

typedef __attribute__((ext_vector_type(8))) __bf16 bf16x8;
typedef __attribute__((ext_vector_type(4))) float f32x4;

__device__ __forceinline__ unsigned short f2bf(float f) {
    unsigned int u = __builtin_bit_cast(unsigned int, f);
    u += 0x7fffu + ((u >> 16) & 1u);
    return (unsigned short)(u >> 16);
}

// ---------------- LayerNorm: x fp32 [B][D] -> h bf16 [B][D] ----------------
__global__ __launch_bounds__(256) void ln_kernel(
    const float* __restrict__ x, const float* __restrict__ gamma,
    const float* __restrict__ beta, unsigned short* __restrict__ h)
{
    const int row = blockIdx.x;
    const int t = threadIdx.x;
    const float4* x4 = reinterpret_cast<const float4*>(x + (long)row * D_MODEL);
    float4 a = x4[t];
    float4 b = x4[256 + t];
    float s  = a.x + a.y + a.z + a.w + b.x + b.y + b.z + b.w;
    float ss = a.x*a.x + a.y*a.y + a.z*a.z + a.w*a.w
             + b.x*b.x + b.y*b.y + b.z*b.z + b.w*b.w;
    #pragma unroll
    for (int off = 32; off; off >>= 1) {
        s  += __shfl_xor(s, off);
        ss += __shfl_xor(ss, off);
    }
    __shared__ float red[8];
    const int lane = t & 63, wid = t >> 6;
    if (lane == 0) { red[wid*2] = s; red[wid*2+1] = ss; }
    __syncthreads();
    s  = red[0] + red[2] + red[4] + red[6];
    ss = red[1] + red[3] + red[5] + red[7];
    const float mean = s * (1.0f / D_MODEL);
    const float var  = ss * (1.0f / D_MODEL) - mean * mean;
    const float inv  = rsqrtf(var + 1e-5f);

    const float4* g4  = reinterpret_cast<const float4*>(gamma);
    const float4* be4 = reinterpret_cast<const float4*>(beta);
    ushort4* h4 = reinterpret_cast<ushort4*>(h + (long)row * D_MODEL);
    {
        float4 g = g4[t], be = be4[t];
        ushort4 o;
        o.x = f2bf((a.x - mean) * inv * g.x + be.x);
        o.y = f2bf((a.y - mean) * inv * g.y + be.y);
        o.z = f2bf((a.z - mean) * inv * g.z + be.z);
        o.w = f2bf((a.w - mean) * inv * g.w + be.w);
        h4[t] = o;
    }
    {
        float4 g = g4[256 + t], be = be4[256 + t];
        ushort4 o;
        o.x = f2bf((b.x - mean) * inv * g.x + be.x);
        o.y = f2bf((b.y - mean) * inv * g.y + be.y);
        o.z = f2bf((b.z - mean) * inv * g.z + be.z);
        o.w = f2bf((b.w - mean) * inv * g.w + be.w);
        h4[256 + t] = o;
    }
}

// ------------- transpose + convert: out[k][j] = bf16(in[j][k]) -------------
__global__ __launch_bounds__(256) void transpose_f32_to_bf16(
    const float* __restrict__ in, unsigned short* __restrict__ out, int Dm)
{
    __shared__ float tile[32][33];
    const int nb = Dm >> 5;
    const int k0 = (blockIdx.x % nb) * 32;
    const int j0 = (blockIdx.x / nb) * 32;
    const int tx = threadIdx.x & 31, ty0 = threadIdx.x >> 5;
    #pragma unroll
    for (int i = 0; i < 32; i += 8) {
        int j = ty0 + i;
        tile[j][tx] = in[(long)(j0 + j) * Dm + k0 + tx];
    }
    __syncthreads();
    #pragma unroll
    for (int i = 0; i < 32; i += 8) {
        int kk = ty0 + i;
        out[(long)(k0 + kk) * Dm + j0 + tx] = f2bf(tile[tx][kk]);
    }
}

// ---------------- elementwise convert fp32 -> bf16 ----------------
__global__ __launch_bounds__(256) void convert_bf16(
    const float* __restrict__ in, unsigned short* __restrict__ out, long n)
{
    long i = ((long)blockIdx.x * 256 + threadIdx.x) * 8;
    if (i >= n) return;
    const float4* in4 = reinterpret_cast<const float4*>(in + i);
    float4 a = in4[0], b = in4[1];
    union { unsigned short u[8]; uint4 v; } o;
    o.u[0] = f2bf(a.x); o.u[1] = f2bf(a.y); o.u[2] = f2bf(a.z); o.u[3] = f2bf(a.w);
    o.u[4] = f2bf(b.x); o.u[5] = f2bf(b.y); o.u[6] = f2bf(b.z); o.u[7] = f2bf(b.w);
    *reinterpret_cast<uint4*>(out + i) = o.v;
}

// ---------------- b_c[n] = b_o[n] + sum_j w_o[n][j]*b_v[j] (fp32) ----------------
__global__ __launch_bounds__(256) void bias_combine(
    const float* __restrict__ w_o, const float* __restrict__ b_v,
    const float* __restrict__ b_o, float* __restrict__ b_c)
{
    const int n = blockIdx.x;
    const int t = threadIdx.x;
    const float4* w4 = reinterpret_cast<const float4*>(w_o + (long)n * D_MODEL);
    const float4* v4 = reinterpret_cast<const float4*>(b_v);
    float4 a = w4[t], b = w4[256 + t], va = v4[t], vb = v4[256 + t];
    float s = a.x*va.x + a.y*va.y + a.z*va.z + a.w*va.w
            + b.x*vb.x + b.y*vb.y + b.z*vb.z + b.w*vb.w;
    #pragma unroll
    for (int off = 32; off; off >>= 1) s += __shfl_xor(s, off);
    __shared__ float red[4];
    const int lane = t & 63, wid = t >> 6;
    if (lane == 0) red[wid] = s;
    __syncthreads();
    if (t == 0) b_c[n] = red[0] + red[1] + red[2] + red[3] + b_o[n];
}

// ---------------- small BT-GEMM (128x128 tile, m97 structure), bf16 out ----------------
__global__ __launch_bounds__(256, 2) void gemm_bt_128(
    const unsigned short* __restrict__ A, const unsigned short* __restrict__ B,
    unsigned short* __restrict__ C, int M, int N, int K)
{
    const int nBN = N >> 7;
    int wg = blockIdx.x;
    const int nwg = gridDim.x;
    const int cpx = nwg >> 3;
    wg = (wg & 7) * cpx + (wg >> 3);
    const int bm = wg / nBN, bn = wg % nBN;

    const int t = threadIdx.x;
    const int lane = t & 63, wid = t >> 6;
    const int wr = wid >> 1, wc = wid & 1;

    __shared__ __align__(16) unsigned short Alds[128 * 32];
    __shared__ __align__(16) unsigned short Blds[128 * 32];

    f32x4 acc[4][4];
    #pragma unroll
    for (int i = 0; i < 4; i++)
        #pragma unroll
        for (int j = 0; j < 4; j++) acc[i][j] = (f32x4){0.f, 0.f, 0.f, 0.f};

    const long Abase = (long)bm * 128 * K;
    const long Bbase = (long)bn * 128 * K;
    const int ci0 = wid * 64 + lane;
    const int ci1 = 256 + ci0;
    const int r0 = ci0 >> 2, c0 = (ci0 & 3) * 8;
    const int r1 = ci1 >> 2, c1 = (ci1 & 3) * 8;

    const int arow = wr * 64 + (lane & 15);
    const int brow = wc * 64 + (lane & 15);
    const int koff = (lane >> 4) * 8;

    for (int k0 = 0; k0 < K; k0 += 32) {
        __builtin_amdgcn_global_load_lds(
            (const __attribute__((address_space(1))) void*)(A + Abase + (long)r0 * K + k0 + c0),
            (__attribute__((address_space(3))) void*)(Alds + wid * 512), 16, 0, 0);
        __builtin_amdgcn_global_load_lds(
            (const __attribute__((address_space(1))) void*)(A + Abase + (long)r1 * K + k0 + c1),
            (__attribute__((address_space(3))) void*)(Alds + 2048 + wid * 512), 16, 0, 0);
        __builtin_amdgcn_global_load_lds(
            (const __attribute__((address_space(1))) void*)(B + Bbase + (long)r0 * K + k0 + c0),
            (__attribute__((address_space(3))) void*)(Blds + wid * 512), 16, 0, 0);
        __builtin_amdgcn_global_load_lds(
            (const __attribute__((address_space(1))) void*)(B + Bbase + (long)r1 * K + k0 + c1),
            (__attribute__((address_space(3))) void*)(Blds + 2048 + wid * 512), 16, 0, 0);
        __syncthreads();

        bf16x8 af[4], bfr[4];
        #pragma unroll
        for (int m = 0; m < 4; m++)
            af[m] = *reinterpret_cast<const bf16x8*>(&Alds[(arow + m * 16) * 32 + koff]);
        #pragma unroll
        for (int n = 0; n < 4; n++)
            bfr[n] = *reinterpret_cast<const bf16x8*>(&Blds[(brow + n * 16) * 32 + koff]);
        #pragma unroll
        for (int m = 0; m < 4; m++)
            #pragma unroll
            for (int n = 0; n < 4; n++)
                acc[m][n] = __builtin_amdgcn_mfma_f32_16x16x32_bf16(af[m], bfr[n], acc[m][n], 0, 0, 0);
        __syncthreads();
    }

    const int crow0 = bm * 128 + wr * 64 + ((lane >> 4) << 2);
    const int ccol0 = bn * 128 + wc * 64 + (lane & 15);
    #pragma unroll
    for (int m = 0; m < 4; m++)
        #pragma unroll
        for (int j = 0; j < 4; j++) {
            const long r = crow0 + m * 16 + j;
            #pragma unroll
            for (int n = 0; n < 4; n++)
                C[r * N + ccol0 + n * 16] = f2bf(acc[m][n][j]);
        }
}

// ======== big BT-GEMM: 256x256 tile, BK=32, 8 waves, counted-vmcnt pipeline ========
// C[m][n] = sum_k A[m][k]*B[n][k] + bias[n] + resid[m][n], fp32 out.
// LDS: 4 buffers x (A 256x32 | B 256x32) bf16 = 4 x 32 KiB. Stage 3 tiles ahead.
// Swizzle (rule 21, both sides): row stride 64 B = 4 x 16B slots; LDS slot
// (r, c) holds global k-chunk c ^ ((r>>2)&3).  Read pattern then lands on
// 128B-window slot (4*l15 + (l4 ^ (l15>>2))) mod 8 -> each of 8 slots hit
// exactly 2x per 16-lane group -> 2-way = free (m136).  [Round-3's c^(r&3)
// gave only 4 distinct slots -> 4-way conflict -> the 1.26e7 counter.]
// Per tile: 2 phases (16 MFMA each, setprio-wrapped); phase 0 stages A(kt+3),
// phase 1 stages B(kt+3). Counted s_waitcnt vmcnt(8) at tile start (2 newer
// tiles x 4 loads stay in flight); tail drains 8->4->0. Never drain-0 mid-loop.
__global__ __launch_bounds__(512, 2) void gemm_bt_256(
    const unsigned short* __restrict__ A, const unsigned short* __restrict__ B,
    float* __restrict__ C, const float* __restrict__ bias,
    const float* __restrict__ resid, int M, int N, int K)
{
    __shared__ __align__(16) char lds[131072];   // 4 x [A 16K | B 16K]

    const int nBN = N >> 8;
    int wg = blockIdx.x;
    const int cpx = gridDim.x >> 3;     // nwg % 8 == 0 (512)
    wg = (wg & 7) * cpx + (wg >> 3);
    const int bm = wg / nBN, bn = wg % nBN;

    const int t = threadIdx.x;
    const int lane = t & 63, wid = t >> 6;
    const int wr = wid >> 2;            // 0..1 : wave row (128 rows)
    const int wcn = wid & 3;            // 0..3 : wave col (64 cols)

    // staging source (inverse-swizzled): thread t covers LDS slot (r_lo, t&3)
    const int r_lo = t >> 2, cch = t & 3;
    const int schunk = (cch ^ ((r_lo >> 2) & 3)) * 8;   // element offset of source chunk
    const unsigned short* sA0 = A + (long)(bm * 256 + r_lo) * K + schunk;
    const unsigned short* sA1 = sA0 + (long)128 * K;
    const unsigned short* sB0 = B + (long)(bn * 256 + r_lo) * K + schunk;
    const unsigned short* sB1 = sB0 + (long)128 * K;

#define STAGE_A(d) do { \
    __builtin_amdgcn_global_load_lds((const __attribute__((address_space(1))) void*)sA0, \
        (__attribute__((address_space(3))) void*)(lds + (d) * 32768 + wid * 1024), 16, 0, 0); \
    __builtin_amdgcn_global_load_lds((const __attribute__((address_space(1))) void*)sA1, \
        (__attribute__((address_space(3))) void*)(lds + (d) * 32768 + 8192 + wid * 1024), 16, 0, 0); \
    sA0 += 32; sA1 += 32; } while (0)
#define STAGE_B(d) do { \
    __builtin_amdgcn_global_load_lds((const __attribute__((address_space(1))) void*)sB0, \
        (__attribute__((address_space(3))) void*)(lds + (d) * 32768 + 16384 + wid * 1024), 16, 0, 0); \
    __builtin_amdgcn_global_load_lds((const __attribute__((address_space(1))) void*)sB1, \
        (__attribute__((address_space(3))) void*)(lds + (d) * 32768 + 24576 + wid * 1024), 16, 0, 0); \
    sB0 += 32; sB1 += 32; } while (0)

    // ds_read addressing (swizzled): row stride 64 B, chunk = l4 ^ ((row>>2)&3)
    const int l15 = lane & 15, l4 = lane >> 4;
    const int koffb = ((l4 ^ ((l15 >> 2) & 3)) << 4);
    const int aRowB = (wr * 128 + l15) * 64 + koffb;           // + m*1024 (+4096 for mh=1)
    const int bRowB = 16384 + (wcn * 64 + l15) * 64 + koffb;   // + n*1024

    f32x4 acc[8][4];
    #pragma unroll
    for (int i = 0; i < 8; i++)
        #pragma unroll
        for (int j = 0; j < 4; j++) acc[i][j] = (f32x4){0.f, 0.f, 0.f, 0.f};

    const int nt = K >> 5;              // 64 tiles
    // prologue: stage tiles 0,1,2 (A before B per tile, matching loop order)
    STAGE_A(0); STAGE_B(0);
    STAGE_A(1); STAGE_B(1);
    STAGE_A(2); STAGE_B(2);

    for (int kt = 0; kt < nt; ++kt) {
        const int bufb = (kt & 3) * 32768;
        const int slack = nt - 1 - kt;
        // counted wait: keep 4 loads per not-yet-needed tile in flight
        if (slack >= 2)      asm volatile("s_waitcnt vmcnt(8)" ::: "memory");
        else if (slack == 1) asm volatile("s_waitcnt vmcnt(4)" ::: "memory");
        else                 asm volatile("s_waitcnt vmcnt(0)" ::: "memory");
        __builtin_amdgcn_s_barrier();
        __builtin_amdgcn_sched_barrier(0);

        bf16x8 af[4], bfr[4];
        #pragma unroll
        for (int n = 0; n < 4; n++)
            bfr[n] = *reinterpret_cast<const bf16x8*>(lds + bufb + bRowB + n * 1024);
        #pragma unroll
        for (int m = 0; m < 4; m++)
            af[m] = *reinterpret_cast<const bf16x8*>(lds + bufb + aRowB + m * 1024);
        if (kt + 3 < nt) STAGE_A((kt + 3) & 3);
        __builtin_amdgcn_s_setprio(1);
        #pragma unroll
        for (int m = 0; m < 4; m++)
            #pragma unroll
            for (int n = 0; n < 4; n++)
                acc[m][n] = __builtin_amdgcn_mfma_f32_16x16x32_bf16(af[m], bfr[n], acc[m][n], 0, 0, 0);
        __builtin_amdgcn_s_setprio(0);

        __builtin_amdgcn_s_barrier();
        __builtin_amdgcn_sched_barrier(0);

        #pragma unroll
        for (int m = 0; m < 4; m++)
            af[m] = *reinterpret_cast<const bf16x8*>(lds + bufb + aRowB + 4096 + m * 1024);
        if (kt + 3 < nt) STAGE_B((kt + 3) & 3);
        __builtin_amdgcn_s_setprio(1);
        #pragma unroll
        for (int m = 0; m < 4; m++)
            #pragma unroll
            for (int n = 0; n < 4; n++)
                acc[4 + m][n] = __builtin_amdgcn_mfma_f32_16x16x32_bf16(af[m], bfr[n], acc[4 + m][n], 0, 0, 0);
        __builtin_amdgcn_s_setprio(0);
    }
#undef STAGE_A
#undef STAGE_B

    // epilogue: C = acc + bias[col] + resid[row][col]
    const int crow0 = bm * 256 + wr * 128 + l4 * 4;
    const int ccol0 = bn * 256 + wcn * 64 + l15;
    #pragma unroll
    for (int m = 0; m < 8; m++)
        #pragma unroll
        for (int j = 0; j < 4; j++) {
            const long r = crow0 + m * 16 + j;
            float* crow = C + r * N;
            const float* rrow = resid + r * N;
            #pragma unroll
            for (int n = 0; n < 4; n++) {
                const int col = ccol0 + n * 16;
                crow[col] = acc[m][n][j] + bias[col] + rrow[col];
            }
        }
}

extern "C" void kernel_launch(void* const* d_in, const int* in_sizes, int n_in,
                              void* d_out, int out_size, void* d_ws, size_t ws_size,
                              hipStream_t stream) {
    // setup_inputs order: x, w_q, b_q, w_k, b_k, w_v, b_v, w_o, b_o, ln_gamma, ln_beta
    const float* x     = (const float*)d_in[0];
    const float* w_v   = (const float*)d_in[5];
    const float* b_v   = (const float*)d_in[6];
    const float* w_o   = (const float*)d_in[7];
    const float* b_o   = (const float*)d_in[8];
    const float* gamma = (const float*)d_in[9];
    const float* beta  = (const float*)d_in[10];
    float* out = (float*)d_out;

    char* ws = (char*)d_ws;
    unsigned short* h   = (unsigned short*)(ws);                              // 64 MiB
    unsigned short* wvT = (unsigned short*)(ws + 67108864L);                  // 8 MiB
    unsigned short* woB = (unsigned short*)(ws + 67108864L + 8388608L);       // 8 MiB
    unsigned short* Wc  = (unsigned short*)(ws + 67108864L + 2 * 8388608L);   // 8 MiB
    float*          b_c = (float*)(ws + 67108864L + 3 * 8388608L);            // 8 KiB

    // 1) h = LN(x) in bf16
    ln_kernel<<<N_BATCH, 256, 0, stream>>>(x, gamma, beta, h);
    // 2) wvT[k][j] = bf16(w_v[j][k])
    transpose_f32_to_bf16<<<(D_MODEL / 32) * (D_MODEL / 32), 256, 0, stream>>>(w_v, wvT, D_MODEL);
    // 3) woB = bf16(w_o)
    convert_bf16<<<(D_MODEL * (long)D_MODEL) / (256 * 8), 256, 0, stream>>>(w_o, woB, (long)D_MODEL * D_MODEL);
    // 4) b_c = w_o @ b_v + b_o (fp32)
    bias_combine<<<D_MODEL, 256, 0, stream>>>(w_o, b_v, b_o, b_c);
    // 5) Wc[n][k] = sum_j w_o[n][j] * w_v[j][k]
    gemm_bt_128<<<(D_MODEL / 128) * (D_MODEL / 128), 256, 0, stream>>>(
        woB, wvT, Wc, D_MODEL, D_MODEL, D_MODEL);
    // 6) out[b][n] = sum_k h[b][k] * Wc[n][k] + b_c[n] + x[b][n]
    gemm_bt_256<<<(N_BATCH / 256) * (D_MODEL / 256), 512, 0, stream>>>(
        h, Wc, out, b_c, x, N_BATCH, D_MODEL, D_MODEL);
}